// Round 1
// baseline (5699.046 us; speedup 1.0000x reference)
//
#include <hip/hip_runtime.h>

// ---------------------------------------------------------------------------
// BernNet forward: x@W1+b1 -> relu -> 2x BernConv(K=10) -> h@W2+b2
// Propagation is pull-based over a CSR (edges sorted by dst), fused so each
// Chebyshev step is a single kernel (agg + recurrence + out accumulation).
// ---------------------------------------------------------------------------

#define SCAN_BLOCK 256
#define SCAN_ITEMS 4
#define SCAN_CHUNK 1024

__global__ __launch_bounds__(256) void hist_kernel(const int* __restrict__ src,
                                                   const int* __restrict__ dst,
                                                   int* __restrict__ deg_src,
                                                   int* __restrict__ cnt_dst, int E) {
    int stride = gridDim.x * blockDim.x;
    for (int e = blockIdx.x * blockDim.x + threadIdx.x; e < E; e += stride) {
        atomicAdd(&deg_src[src[e]], 1);
        atomicAdd(&cnt_dst[dst[e]], 1);
    }
}

__global__ __launch_bounds__(256) void dinv_kernel(const int* __restrict__ deg,
                                                   float* __restrict__ dinv, int n) {
    int i = blockIdx.x * blockDim.x + threadIdx.x;
    if (i < n) {
        int d = deg[i];
        dinv[i] = d > 0 ? rsqrtf((float)d) : 0.f;
    }
}

__global__ __launch_bounds__(SCAN_BLOCK) void scan_chunk_sum(const int* __restrict__ cnt,
                                                             int* __restrict__ bsum, int n) {
    __shared__ int sdata[SCAN_BLOCK];
    int tid = threadIdx.x;
    int base = blockIdx.x * SCAN_CHUNK + tid * SCAN_ITEMS;
    int s = 0;
    for (int i = 0; i < SCAN_ITEMS; ++i) {
        int idx = base + i;
        if (idx < n) s += cnt[idx];
    }
    sdata[tid] = s;
    __syncthreads();
    for (int off = SCAN_BLOCK / 2; off > 0; off >>= 1) {
        if (tid < off) sdata[tid] += sdata[tid + off];
        __syncthreads();
    }
    if (tid == 0) bsum[blockIdx.x] = sdata[0];
}

__global__ void scan_bsum(int* __restrict__ bsum, int nb) {
    if (threadIdx.x == 0 && blockIdx.x == 0) {
        int run = 0;
        for (int i = 0; i < nb; ++i) {
            int v = bsum[i];
            bsum[i] = run;
            run += v;
        }
    }
}

__global__ __launch_bounds__(SCAN_BLOCK) void scan_write(const int* __restrict__ cnt,
                                                         const int* __restrict__ bsum,
                                                         int* __restrict__ rowptr, int n, int total) {
    __shared__ int sdata[SCAN_BLOCK];
    int tid = threadIdx.x;
    int base = blockIdx.x * SCAN_CHUNK + tid * SCAN_ITEMS;
    int vals[SCAN_ITEMS];
    int s = 0;
    for (int i = 0; i < SCAN_ITEMS; ++i) {
        int idx = base + i;
        vals[i] = (idx < n) ? cnt[idx] : 0;
        s += vals[i];
    }
    sdata[tid] = s;
    __syncthreads();
    // Hillis-Steele inclusive scan
    for (int off = 1; off < SCAN_BLOCK; off <<= 1) {
        int add = (tid >= off) ? sdata[tid - off] : 0;
        __syncthreads();
        sdata[tid] += add;
        __syncthreads();
    }
    int run = bsum[blockIdx.x] + sdata[tid] - s;  // exclusive offset for this thread
    for (int i = 0; i < SCAN_ITEMS; ++i) {
        int idx = base + i;
        if (idx < n) rowptr[idx] = run;
        run += vals[i];
    }
    if (blockIdx.x == 0 && tid == 0) rowptr[n] = total;
}

__global__ __launch_bounds__(256) void copy_int_kernel(const int* __restrict__ a,
                                                       int* __restrict__ b, int n) {
    int i = blockIdx.x * blockDim.x + threadIdx.x;
    if (i < n) b[i] = a[i];
}

__global__ __launch_bounds__(256) void scatter_kernel(const int* __restrict__ src,
                                                      const int* __restrict__ dst,
                                                      const float* __restrict__ dinv,
                                                      int* __restrict__ cursor,
                                                      int* __restrict__ col,
                                                      float* __restrict__ wv, int E) {
    int stride = gridDim.x * blockDim.x;
    for (int e = blockIdx.x * blockDim.x + threadIdx.x; e < E; e += stride) {
        int s = src[e];
        int d = dst[e];
        int p = atomicAdd(&cursor[d], 1);
        col[p] = s;
        wv[p] = -0.5f * dinv[s] * dinv[d];
    }
}

// -------------------- GEMM1: h = relu(x @ W1 + b1), K=256, cols=128 --------
#define G1_ROWS 16
__global__ __launch_bounds__(128) void gemm1_kernel(const float* __restrict__ X,
                                                    const float* __restrict__ W,
                                                    const float* __restrict__ b,
                                                    float* __restrict__ H, int n) {
    __shared__ float xt[G1_ROWS][256];
    int j = threadIdx.x;  // output column 0..127
    int r0 = blockIdx.x * G1_ROWS;
    for (int i = threadIdx.x; i < G1_ROWS * 256; i += 128) {
        int r = i >> 8, k = i & 255;
        int row = r0 + r;
        xt[r][k] = (row < n) ? X[(size_t)row * 256 + k] : 0.f;
    }
    __syncthreads();
    float acc[G1_ROWS];
#pragma unroll
    for (int r = 0; r < G1_ROWS; ++r) acc[r] = 0.f;
    for (int k = 0; k < 256; ++k) {
        float wk = W[k * 128 + j];
#pragma unroll
        for (int r = 0; r < G1_ROWS; ++r) acc[r] += xt[r][k] * wk;
    }
    float bj = b[j];
    for (int r = 0; r < G1_ROWS; ++r) {
        int row = r0 + r;
        if (row < n) H[(size_t)row * 128 + j] = fmaxf(acc[r] + bj, 0.f);
    }
}

// -------------------- GEMM2: out = h @ W2 + b2, K=128, cols=64 -------------
#define G2_ROWS 32
__global__ __launch_bounds__(64) void gemm2_kernel(const float* __restrict__ H,
                                                   const float* __restrict__ W,
                                                   const float* __restrict__ b,
                                                   float* __restrict__ O, int n) {
    __shared__ float xt[G2_ROWS][128];
    int j = threadIdx.x;  // output column 0..63
    int r0 = blockIdx.x * G2_ROWS;
    for (int i = threadIdx.x; i < G2_ROWS * 128; i += 64) {
        int r = i >> 7, k = i & 127;
        int row = r0 + r;
        xt[r][k] = (row < n) ? H[(size_t)row * 128 + k] : 0.f;
    }
    __syncthreads();
    float acc[G2_ROWS];
#pragma unroll
    for (int r = 0; r < G2_ROWS; ++r) acc[r] = 0.f;
    for (int k = 0; k < 128; ++k) {
        float wk = W[k * 64 + j];
#pragma unroll
        for (int r = 0; r < G2_ROWS; ++r) acc[r] += xt[r][k] * wk;
    }
    float bj = b[j];
    for (int r = 0; r < G2_ROWS; ++r) {
        int row = r0 + r;
        if (row < n) O[(size_t)row * 64 + j] = acc[r] + bj;
    }
}

// -------------------- Fused Chebyshev propagation step ---------------------
// One wave per node; lane l owns features [2l, 2l+1] (float2).
// agg = sum_e wv[e] * X[col[e]]   (X is the gather source)
// mode 0: X = layer input x;  tx1 = 0.5x - agg  -> TX1;  OUT = c0*x + c1*tx1
// mode 1: X = tx1; tx2 = tx1 - 2*agg - tx0; OUT += ck*tx2; T0 <- tx2 (in place)
// mode 2: same as 1 but T0 <- relu(OUT + ck*tx2) (layer output), OUT untouched
__global__ __launch_bounds__(256) void prop_kernel(const float* __restrict__ X,
                                                   float* __restrict__ T0,
                                                   float* __restrict__ OUT,
                                                   float* __restrict__ TX1,
                                                   const int* __restrict__ rowptr,
                                                   const int* __restrict__ col,
                                                   const float* __restrict__ wv,
                                                   const float* __restrict__ coeffs,
                                                   int cidx, int mode, int n) {
    int wave = (blockIdx.x * blockDim.x + threadIdx.x) >> 6;
    int lane = threadIdx.x & 63;
    if (wave >= n) return;
    int v = wave;
    int start = rowptr[v];
    int end = rowptr[v + 1];

    const float2* __restrict__ Xv = reinterpret_cast<const float2*>(X);
    float accx = 0.f, accy = 0.f;

    for (int e0 = start; e0 < end; e0 += 64) {
        int m = end - e0;
        if (m > 64) m = 64;
        int sE = 0;
        float wE = 0.f;
        if (lane < m) {
            sE = col[e0 + lane];
            wE = wv[e0 + lane];
        }
        for (int j = 0; j < m; ++j) {
            int s = __shfl(sE, j);
            float wt = __shfl(wE, j);
            float2 xs = Xv[(size_t)s * 64 + lane];
            accx += wt * xs.x;
            accy += wt * xs.y;
        }
    }

    size_t idx = (size_t)v * 64 + lane;
    float2 self = Xv[idx];

    if (mode == 0) {
        float c0 = coeffs[cidx];
        float c1 = coeffs[cidx + 1];
        float2 t1 = {0.5f * self.x - accx, 0.5f * self.y - accy};
        reinterpret_cast<float2*>(TX1)[idx] = t1;
        float2 o = {c0 * self.x + c1 * t1.x, c0 * self.y + c1 * t1.y};
        reinterpret_cast<float2*>(OUT)[idx] = o;
    } else {
        float ck = coeffs[cidx];
        float2 t0 = reinterpret_cast<const float2*>(T0)[idx];
        float2 t2 = {self.x - 2.f * accx - t0.x, self.y - 2.f * accy - t0.y};
        float2 o = reinterpret_cast<float2*>(OUT)[idx];
        o.x += ck * t2.x;
        o.y += ck * t2.y;
        if (mode == 1) {
            reinterpret_cast<float2*>(T0)[idx] = t2;  // tx2 overwrites tx0 in place
            reinterpret_cast<float2*>(OUT)[idx] = o;
        } else {
            // final step: layer output = relu(out), stored into T0's buffer
            reinterpret_cast<float2*>(T0)[idx] = {fmaxf(o.x, 0.f), fmaxf(o.y, 0.f)};
        }
    }
}

// ---------------------------------------------------------------------------

extern "C" void kernel_launch(void* const* d_in, const int* in_sizes, int n_in,
                              void* d_out, int out_size, void* d_ws, size_t ws_size,
                              hipStream_t stream) {
    const float* x      = (const float*)d_in[0];
    const int*   ei     = (const int*)d_in[1];
    const float* W1     = (const float*)d_in[2];
    const float* b1     = (const float*)d_in[3];
    const float* coeffs = (const float*)d_in[4];
    const float* W2     = (const float*)d_in[5];
    const float* b2     = (const float*)d_in[6];
    float* out = (float*)d_out;

    const int n = in_sizes[0] / 256;
    const int E = in_sizes[1] / 2;
    const int* src = ei;
    const int* dst = ei + E;

    char* ws = (char*)d_ws;
    size_t off = 0;
    auto alloc = [&](size_t bytes) -> void* {
        off = (off + 255) & ~(size_t)255;
        void* p = (void*)(ws + off);
        off += bytes;
        return p;
    };
    size_t bufBytes = (size_t)n * 128 * sizeof(float);
    float* bufA   = (float*)alloc(bufBytes);
    float* bufB   = (float*)alloc(bufBytes);
    float* bufC   = (float*)alloc(bufBytes);
    int*   col    = (int*)alloc((size_t)E * sizeof(int));
    float* wv     = (float*)alloc((size_t)E * sizeof(float));
    int*   degs   = (int*)alloc((size_t)n * sizeof(int));
    int*   cntd   = (int*)alloc((size_t)n * sizeof(int));
    int*   rowptr = (int*)alloc((size_t)(n + 1) * sizeof(int));
    int*   cursor = (int*)alloc((size_t)n * sizeof(int));
    int*   bsum   = (int*)alloc(1024 * sizeof(int));
    float* dinv   = (float*)alloc((size_t)n * sizeof(float));

    hipMemsetAsync(degs, 0, (size_t)n * sizeof(int), stream);
    hipMemsetAsync(cntd, 0, (size_t)n * sizeof(int), stream);

    // ---- CSR build (by dst) + edge weights ----
    hist_kernel<<<2048, 256, 0, stream>>>(src, dst, degs, cntd, E);
    dinv_kernel<<<(n + 255) / 256, 256, 0, stream>>>(degs, dinv, n);
    int nchunk = (n + SCAN_CHUNK - 1) / SCAN_CHUNK;
    scan_chunk_sum<<<nchunk, SCAN_BLOCK, 0, stream>>>(cntd, bsum, n);
    scan_bsum<<<1, 64, 0, stream>>>(bsum, nchunk);
    scan_write<<<nchunk, SCAN_BLOCK, 0, stream>>>(cntd, bsum, rowptr, n, E);
    copy_int_kernel<<<(n + 255) / 256, 256, 0, stream>>>(rowptr, cursor, n);
    scatter_kernel<<<2048, 256, 0, stream>>>(src, dst, dinv, cursor, col, wv, E);

    // ---- h = relu(x @ W1 + b1) ----
    gemm1_kernel<<<(n + G1_ROWS - 1) / G1_ROWS, 128, 0, stream>>>(x, W1, b1, bufA, n);

    // ---- 2 BernConv layers ----
    int pgrid = (n + 3) / 4;  // 4 waves (nodes) per 256-thread block
    float* A = bufA;
    float* B = bufB;
    float* C = bufC;
    for (int l = 0; l < 2; ++l) {
        // k=0,1 fused: tx1 = 0.5x - agg(x); out = c0*x + c1*tx1
        prop_kernel<<<pgrid, 256, 0, stream>>>(A, A, C, B, rowptr, col, wv, coeffs,
                                               l * 11 + 0, 0, n);
        float* t0 = A;
        float* t1 = B;
        for (int k = 2; k <= 9; ++k) {
            prop_kernel<<<pgrid, 256, 0, stream>>>(t1, t0, C, nullptr, rowptr, col, wv,
                                                   coeffs, l * 11 + k, 1, n);
            float* tmp = t0; t0 = t1; t1 = tmp;  // tx0 <- tx1, tx1 <- tx2
        }
        // k=10: fold in last term and ReLU; layer output lands in t0's buffer
        prop_kernel<<<pgrid, 256, 0, stream>>>(t1, t0, C, nullptr, rowptr, col, wv,
                                               coeffs, l * 11 + 10, 2, n);
        A = t0;  // next layer input
        B = t1;  // free buffer
        // C reused as out accumulator
    }

    // ---- out = h @ W2 + b2 ----
    gemm2_kernel<<<(n + G2_ROWS - 1) / G2_ROWS, 64, 0, stream>>>(A, W2, b2, out, n);
}